// Round 11
// baseline (609.471 us; speedup 1.0000x reference)
//
#include <hip/hip_runtime.h>
#include <hip/hip_cooperative_groups.h>

namespace cg = cooperative_groups;

#define N_NODES 50000
#define D_IN 256
#define D_OUT 128
#define N_POS 1600000
#define N_PRED 500000

#define G_BUCKETS 782        // ceil(50000/64) buckets of 64 nodes
#define SB 640               // scatter chunks
#define CHUNK 2500           // SB*CHUNK == N_POS exactly
#define CAP 4096             // eb segment per bucket (mean 2048, sigma ~45)
#define GEMM_BLOCKS 782      // (N_NODES+63)/64

typedef __attribute__((ext_vector_type(8))) short short8;
typedef __attribute__((ext_vector_type(4))) float f32x4;

// ---- bf16 helpers (RNE) ----
__device__ __forceinline__ unsigned short f2bf(float f) {
    unsigned int u = __float_as_uint(f);
    u += 0x7FFFu + ((u >> 16) & 1u);
    return (unsigned short)(u >> 16);
}
__device__ __forceinline__ unsigned int pk2(float a, float b) {   // bf16(a) | bf16(b)<<16
    unsigned int ua = __float_as_uint(a), ub = __float_as_uint(b);
    ua += 0x7FFFu + ((ua >> 16) & 1u);
    ub += 0x7FFFu + ((ub >> 16) & 1u);
    return (ua >> 16) | (ub & 0xFFFF0000u);
}
__device__ __forceinline__ float bflo(unsigned int u) { return __uint_as_float(u << 16); }
__device__ __forceinline__ float bfhi(unsigned int u) { return __uint_as_float(u & 0xFFFF0000u); }

struct P {
    const int* rows; const int* cols;                 // pos edges (src, dst)
    const float* x; const float* W1; const float* b1;
    const float* Wc; const float* bc;
    const int* esrc; const int* edst; float* out;     // pred edges + output
    unsigned short* Bp; float* bf; int* bfill;
    int* offs; int* ends; float* dinv;
    unsigned int* eb; unsigned short* csr;
    unsigned short* hsb; unsigned short* featb;
};

union SM {
    struct {                       // scatter role (23.5 KB)
        int hist[G_BUCKETS]; int lofs[G_BUCKETS]; int fill2[G_BUCKETS];
        int base[G_BUCKETS]; int part[256]; unsigned int stag[CHUNK];
    } sc;
    struct {                       // gemm role (16 KB)
        unsigned short ot[4][2048];
    } ge;
    struct {                       // csr_build role (25.3 KB)
        unsigned int stag[CAP]; unsigned short stag2[CAP];
        int hist[64]; int lofs[64]; int fill[64];
    } cb;
};

// One cooperative kernel, 5 phases separated by grid.sync().
// All phase bodies are the proven R10 kernels re-plumbed as grid-stride loops.
__global__ __launch_bounds__(256, 4) void mega_k(P p) {
    __shared__ SM sm;
    cg::grid_group grid = cg::this_grid();
    const int t = threadIdx.x;

    // ---------- P0: weight fuse (vb 0..127) + cursor init (vb 128) ----------
    for (int vb = blockIdx.x; vb <= 128; vb += gridDim.x) {
        if (vb == 128) {
            for (int g = t; g < G_BUCKETS; g += 256) p.bfill[g] = g * CAP;
        } else {
            int gid = vb * 256 + t;
            int k = gid >> 7, n = gid & 127;
            float acc = 0.f;
            #pragma unroll 4
            for (int kk = 0; kk < D_IN; ++kk)
                acc += p.W1[k * D_IN + kk] * p.Wc[kk * D_OUT + n];
            int ks = k >> 5, q = (k >> 3) & 3, jj = k & 7;
            int nt = n >> 4, nl = n & 15;
            int lane = q * 16 + nl;
            p.Bp[(((long)(ks * 8 + nt)) * 64 + lane) * 8 + jj] = f2bf(acc);
            if (gid < D_OUT) {
                float accb = 0.f;
                for (int kk = 0; kk < D_IN; ++kk)
                    accb += p.b1[kk] * p.Wc[kk * D_OUT + gid];
                p.bf[gid] = accb;
            }
        }
    }
    grid.sync();

    // ---------- P1: gemm (items 0..781) || scatter (items 782..1421) ----------
    for (int wk = blockIdx.x; wk < GEMM_BLOCKS + SB; wk += gridDim.x) {
        __syncthreads();                          // LDS reuse guard
        if (wk < GEMM_BLOCKS) {
            // gemm role: h = x@Wf + bf (UNscaled), 256 B bf16 rows
            const int wave = t >> 6, lane = t & 63;
            const int q = lane >> 4, ml = lane & 15;
            const int m0 = wk * 64 + wave * 16;
            f32x4 acc[8];
            #pragma unroll
            for (int i = 0; i < 8; ++i) acc[i] = (f32x4){0.f, 0.f, 0.f, 0.f};
            long arow = m0 + ml; if (arow > N_NODES - 1) arow = N_NODES - 1;
            const float* xrow = p.x + arow * D_IN + q * 8;
            const uint4* Bp4 = (const uint4*)p.Bp;
            #pragma unroll
            for (int ks = 0; ks < 8; ++ks) {
                float4 xa = *(const float4*)(xrow + ks * 32);
                float4 xb = *(const float4*)(xrow + ks * 32 + 4);
                union { short8 s; unsigned int u[4]; } af;
                af.u[0] = pk2(xa.x, xa.y);
                af.u[1] = pk2(xa.z, xa.w);
                af.u[2] = pk2(xb.x, xb.y);
                af.u[3] = pk2(xb.z, xb.w);
                #pragma unroll
                for (int nt = 0; nt < 8; ++nt) {
                    union { uint4 v; short8 s; } bu;
                    bu.v = Bp4[(long)(ks * 8 + nt) * 64 + lane];
                    acc[nt] = __builtin_amdgcn_mfma_f32_16x16x32_bf16(af.s, bu.s, acc[nt], 0, 0, 0);
                }
            }
            unsigned short* o = sm.ge.ot[wave];
            #pragma unroll
            for (int nt = 0; nt < 8; ++nt) {
                float bn = p.bf[nt * 16 + ml];
                #pragma unroll
                for (int r = 0; r < 4; ++r)
                    o[(q * 4 + r) * 128 + nt * 16 + ml] = f2bf(acc[nt][r] + bn);
            }
            __syncthreads();
            #pragma unroll
            for (int i = 0; i < 4; ++i) {
                int fb = i * 1024 + lane * 16;
                int v = m0 + (fb >> 8);
                if (v < N_NODES) {
                    uint4 val = *(const uint4*)((const char*)o + fb);
                    *(uint4*)((char*)p.hsb + (long)v * 256 + (fb & 255)) = val;
                }
            }
        } else {
            // scatter role: LDS-bin chunk by bucket, burst-write into eb segments
            int* hist  = sm.sc.hist;  int* lofs = sm.sc.lofs;
            int* fill2 = sm.sc.fill2; int* base = sm.sc.base;
            int* part  = sm.sc.part;  unsigned int* stag = sm.sc.stag;
            for (int i = t; i < G_BUCKETS; i += 256) { hist[i] = 0; fill2[i] = 0; }
            __syncthreads();
            int e0 = (wk - GEMM_BLOCKS) * CHUNK;
            for (int i = t; i < CHUNK; i += 256)
                atomicAdd(&hist[p.cols[e0 + i] >> 6], 1);
            __syncthreads();
            int h[4], p4 = 0;
            #pragma unroll
            for (int i = 0; i < 4; ++i) {
                int idx = 4 * t + i;
                h[i] = (idx < G_BUCKETS) ? hist[idx] : 0;
                p4 += h[i];
            }
            part[t] = p4;
            __syncthreads();
            for (int d = 1; d < 256; d <<= 1) {
                int add = (t >= d) ? part[t - d] : 0;
                __syncthreads();
                part[t] += add;
                __syncthreads();
            }
            int ex = part[t] - p4;
            #pragma unroll
            for (int i = 0; i < 4; ++i) {
                int idx = 4 * t + i;
                if (idx < G_BUCKETS) lofs[idx] = ex;
                ex += h[i];
            }
            __syncthreads();
            for (int g = t; g < G_BUCKETS; g += 256) {
                int c = hist[g];
                base[g] = c ? atomicAdd(&p.bfill[g], c) : 0;
            }
            for (int i = t; i < CHUNK; i += 256) {
                int c = p.cols[e0 + i];
                int g = c >> 6;
                unsigned int u = (unsigned int)p.rows[e0 + i]
                               | ((unsigned int)(c & 63) << 16) | ((unsigned int)g << 22);
                int lp = atomicAdd(&fill2[g], 1);
                stag[lofs[g] + lp] = u;
            }
            __syncthreads();
            for (int i = t; i < CHUNK; i += 256) {
                unsigned int u = stag[i];
                int g = u >> 22;
                p.eb[base[g] + (i - lofs[g])] = u;
            }
        }
    }
    grid.sync();

    // ---------- P2: per-bucket CSR build (node-sorted ushort rows; offs/ends/dinv) ----------
    for (int g = blockIdx.x; g < G_BUCKETS; g += gridDim.x) {
        __syncthreads();
        int s = g * CAP;
        int cnt = p.bfill[g] - s;
        if (t < 64) { sm.cb.hist[t] = 0; sm.cb.fill[t] = 0; }
        __syncthreads();
        for (int i = t; i < cnt; i += 256) {
            unsigned int u = p.eb[s + i];
            sm.cb.stag[i] = u;
            atomicAdd(&sm.cb.hist[(u >> 16) & 63], 1);
        }
        __syncthreads();
        if (t == 0) {
            int run = 0;
            for (int k = 0; k < 64; ++k) { sm.cb.lofs[k] = run; run += sm.cb.hist[k]; }
        }
        __syncthreads();
        if (t < 64) {
            int v = g * 64 + t;
            if (v < N_NODES) {
                p.offs[v] = s + sm.cb.lofs[t];
                p.ends[v] = s + sm.cb.lofs[t] + sm.cb.hist[t];
                p.dinv[v] = rsqrtf((float)sm.cb.hist[t] + 1.0f);   // +1 self loop
            }
        }
        for (int i = t; i < cnt; i += 256) {
            unsigned int u = sm.cb.stag[i];
            int nl = (u >> 16) & 63;
            int lp = atomicAdd(&sm.cb.fill[nl], 1);
            sm.cb.stag2[sm.cb.lofs[nl] + lp] = (unsigned short)(u & 0xFFFF);
        }
        __syncthreads();
        for (int i = t; i < cnt; i += 256)
            p.csr[s + i] = sm.cb.stag2[i];
    }
    grid.sync();

    // ---------- P3: aggregation + finalize (16 lanes/edge x uint4, dinv on the fly) ----------
    {
        const uint4* hs4 = (const uint4*)p.hsb;
        uint4* feat4 = (uint4*)p.featb;
        int lane = t & 63, grp = lane >> 4, li = lane & 15;
        for (int vb = blockIdx.x; vb < N_NODES / 4; vb += gridDim.x) {
            int v = vb * 4 + (t >> 6);
            int s0 = p.offs[v], s1 = p.ends[v];
            float a[8] = {0.f, 0.f, 0.f, 0.f, 0.f, 0.f, 0.f, 0.f};
            int i = s0 + grp;
            for (; i + 4 < s1; i += 8) {
                int r0 = p.csr[i], r1 = p.csr[i + 4];
                uint4 u0 = hs4[r0 * 16 + li];
                uint4 u1 = hs4[r1 * 16 + li];
                float d0 = p.dinv[r0], d1 = p.dinv[r1];
                a[0] = fmaf(d0, bflo(u0.x), a[0]); a[0] = fmaf(d1, bflo(u1.x), a[0]);
                a[1] = fmaf(d0, bfhi(u0.x), a[1]); a[1] = fmaf(d1, bfhi(u1.x), a[1]);
                a[2] = fmaf(d0, bflo(u0.y), a[2]); a[2] = fmaf(d1, bflo(u1.y), a[2]);
                a[3] = fmaf(d0, bfhi(u0.y), a[3]); a[3] = fmaf(d1, bfhi(u1.y), a[3]);
                a[4] = fmaf(d0, bflo(u0.z), a[4]); a[4] = fmaf(d1, bflo(u1.z), a[4]);
                a[5] = fmaf(d0, bfhi(u0.z), a[5]); a[5] = fmaf(d1, bfhi(u1.z), a[5]);
                a[6] = fmaf(d0, bflo(u0.w), a[6]); a[6] = fmaf(d1, bflo(u1.w), a[6]);
                a[7] = fmaf(d0, bfhi(u0.w), a[7]); a[7] = fmaf(d1, bfhi(u1.w), a[7]);
            }
            if (i < s1) {
                int r = p.csr[i];
                uint4 u = hs4[r * 16 + li];
                float d = p.dinv[r];
                a[0] = fmaf(d, bflo(u.x), a[0]); a[1] = fmaf(d, bfhi(u.x), a[1]);
                a[2] = fmaf(d, bflo(u.y), a[2]); a[3] = fmaf(d, bfhi(u.y), a[3]);
                a[4] = fmaf(d, bflo(u.z), a[4]); a[5] = fmaf(d, bfhi(u.z), a[5]);
                a[6] = fmaf(d, bflo(u.w), a[6]); a[7] = fmaf(d, bfhi(u.w), a[7]);
            }
            #pragma unroll
            for (int j = 0; j < 8; ++j) {
                a[j] += __shfl_xor(a[j], 16);
                a[j] += __shfl_xor(a[j], 32);
            }
            if (grp == 0) {
                uint4 su = hs4[v * 16 + li];
                float dv = p.dinv[v];
                float4 b0 = *(const float4*)(p.bc + li * 8);
                float4 b1 = *(const float4*)(p.bc + li * 8 + 4);
                float f0 = dv * (a[0] + dv * bflo(su.x)) + b0.x;
                float f1 = dv * (a[1] + dv * bfhi(su.x)) + b0.y;
                float f2 = dv * (a[2] + dv * bflo(su.y)) + b0.z;
                float f3 = dv * (a[3] + dv * bfhi(su.y)) + b0.w;
                float f4 = dv * (a[4] + dv * bflo(su.z)) + b1.x;
                float f5 = dv * (a[5] + dv * bfhi(su.z)) + b1.y;
                float f6 = dv * (a[6] + dv * bflo(su.w)) + b1.z;
                float f7 = dv * (a[7] + dv * bfhi(su.w)) + b1.w;
                uint4 o;
                o.x = pk2(f0, f1); o.y = pk2(f2, f3); o.z = pk2(f4, f5); o.w = pk2(f6, f7);
                feat4[v * 16 + li] = o;
            }
        }
    }
    grid.sync();

    // ---------- P4: scoring (16 lanes/edge) ----------
    {
        const uint4* feat4 = (const uint4*)p.featb;
        for (int vb = blockIdx.x; vb < (N_PRED * 16) / 256; vb += gridDim.x) {
            int gid = vb * 256 + t;
            int e = gid >> 4, c = gid & 15;
            int a = p.esrc[e], b = p.edst[e];
            uint4 ua = feat4[(long)a * 16 + c];
            uint4 ub = feat4[(long)b * 16 + c];
            float pr = bflo(ua.x) * bflo(ub.x) + bfhi(ua.x) * bfhi(ub.x)
                     + bflo(ua.y) * bflo(ub.y) + bfhi(ua.y) * bfhi(ub.y)
                     + bflo(ua.z) * bflo(ub.z) + bfhi(ua.z) * bfhi(ub.z)
                     + bflo(ua.w) * bflo(ub.w) + bfhi(ua.w) * bfhi(ub.w);
            #pragma unroll
            for (int m = 8; m; m >>= 1) pr += __shfl_xor(pr, m, 16);
            if (c == 0) p.out[e] = pr;
        }
    }
}

extern "C" void kernel_launch(void* const* d_in, const int* in_sizes, int n_in,
                              void* d_out, int out_size, void* d_ws, size_t ws_size,
                              hipStream_t stream) {
    const float* x   = (const float*)d_in[0];
    const int*   ei  = (const int*)  d_in[1];   // [2, N_PRED]
    const int*   pe  = (const int*)  d_in[2];   // [2, N_POS]
    const float* W1  = (const float*)d_in[3];
    const float* b1  = (const float*)d_in[4];
    const float* Wc  = (const float*)d_in[5];
    const float* bc  = (const float*)d_in[6];

    // workspace layout (16B-aligned blocks)
    char* w = (char*)d_ws;
    unsigned short* Bp = (unsigned short*)w;  w += 32768 * 2;      // 64 KB
    float* bf    = (float*)w;                 w += 128 * 4;
    float* dinv  = (float*)w;                 w += 50000 * 4;
    int*   bfill = (int*)w;                   w += 1024 * 4;
    int*   offs  = (int*)w;                   w += 50000 * 4;
    int*   ends  = (int*)w;                   w += 50000 * 4;
    unsigned int* eb = (unsigned int*)w;      w += (long)G_BUCKETS * CAP * 4;    // 12.81 MB
    unsigned short* csr = (unsigned short*)w; w += (long)G_BUCKETS * CAP * 2;    // 6.4 MB
    unsigned short* hsb   = (unsigned short*)w;  w += (long)N_NODES * D_OUT * 2; // 12.8 MB
    unsigned short* featb = (unsigned short*)w;  // 12.8 MB

    P p;
    p.rows = pe;             p.cols = pe + N_POS;
    p.x = x; p.W1 = W1; p.b1 = b1; p.Wc = Wc; p.bc = bc;
    p.esrc = ei;             p.edst = ei + N_PRED;
    p.out = (float*)d_out;
    p.Bp = Bp; p.bf = bf; p.bfill = bfill;
    p.offs = offs; p.ends = ends; p.dinv = dinv;
    p.eb = eb; p.csr = csr; p.hsb = hsb; p.featb = featb;

    // cooperative grid: all blocks co-resident (required for grid.sync)
    int occ = 0;
    hipOccupancyMaxActiveBlocksPerMultiprocessor(&occ, mega_k, 256, 0);
    if (occ < 1) occ = 1;
    if (occ > 8) occ = 8;
    int grid = occ * 256;          // 256 CUs on MI355X

    void* args[] = { &p };
    hipLaunchCooperativeKernel((void*)mega_k, dim3(grid), dim3(256), args, 0, stream);
}

// Round 12
// 268.192 us; speedup vs baseline: 2.2725x; 2.2725x over previous
//
#include <hip/hip_runtime.h>

#define N_NODES 50000
#define D_IN 256
#define D_OUT 128
#define N_POS 1600000
#define N_PRED 500000

#define G_BUCKETS 782        // ceil(50000/64) buckets of 64 nodes
#define GPAD 1024
#define SB 640               // scatter blocks
#define CHUNK 2500           // SB*CHUNK == N_POS exactly
#define CAP 4096             // eb segment per bucket (mean 2048, sigma ~45)
#define GEMM_BLOCKS 782      // (N_NODES+63)/64

typedef __attribute__((ext_vector_type(8))) short short8;
typedef __attribute__((ext_vector_type(4))) float f32x4;

// ---- bf16 helpers (RNE) ----
__device__ __forceinline__ unsigned short f2bf(float f) {
    unsigned int u = __float_as_uint(f);
    u += 0x7FFFu + ((u >> 16) & 1u);
    return (unsigned short)(u >> 16);
}
__device__ __forceinline__ unsigned int pk2(float a, float b) {   // bf16(a) | bf16(b)<<16
    unsigned int ua = __float_as_uint(a), ub = __float_as_uint(b);
    ua += 0x7FFFu + ((ua >> 16) & 1u);
    ub += 0x7FFFu + ((ub >> 16) & 1u);
    return (ua >> 16) | (ub & 0xFFFF0000u);
}
__device__ __forceinline__ float bflo(unsigned int u) { return __uint_as_float(u << 16); }
__device__ __forceinline__ float bfhi(unsigned int u) { return __uint_as_float(u & 0xFFFF0000u); }

// ------- Wf = W1@Wc packed into MFMA B-frag layout; bf = b1@Wc; block 128 inits bfill -------
__global__ void fuse_weights_k(const float* __restrict__ W1, const float* __restrict__ Wc,
                               const float* __restrict__ b1,
                               unsigned short* __restrict__ Bp, float* __restrict__ bf,
                               int* __restrict__ bfill) {
    if (blockIdx.x == 128) {           // segment-cursor init role
        for (int g = threadIdx.x; g < G_BUCKETS; g += 256) bfill[g] = g * CAP;
        return;
    }
    int gid = blockIdx.x * blockDim.x + threadIdx.x;   // 0..32767
    int k = gid >> 7;          // K dim
    int n = gid & 127;         // N dim
    float acc = 0.f;
    #pragma unroll 4
    for (int kk = 0; kk < D_IN; ++kk)
        acc += W1[k * D_IN + kk] * Wc[kk * D_OUT + n];
    int ks = k >> 5, q = (k >> 3) & 3, jj = k & 7;
    int nt = n >> 4, nl = n & 15;
    int lane = q * 16 + nl;
    Bp[(((long)(ks * 8 + nt)) * 64 + lane) * 8 + jj] = f2bf(acc);
    if (gid < D_OUT) {
        float accb = 0.f;
        for (int kk = 0; kk < D_IN; ++kk)
            accb += b1[kk] * Wc[kk * D_OUT + gid];
        bf[gid] = accb;
    }
}

// ------- fused launch: blocks [0,782) MFMA gemm (h = x@Wf+bf, UNscaled);
//         blocks [782, 782+640) bucket scatter into eb segments -------
__global__ __launch_bounds__(256) void scatter_gemm_k(const int* __restrict__ row,
                                                      const int* __restrict__ col,
                                                      int* __restrict__ bfill,
                                                      unsigned int* __restrict__ eb,
                                                      const float* __restrict__ x,
                                                      const uint4* __restrict__ Bp,
                                                      const float* __restrict__ bf,
                                                      unsigned short* __restrict__ hsb) {
    __shared__ __align__(16) char smem[27456];
    if (blockIdx.x < GEMM_BLOCKS) {
        // ---------------- gemm role ----------------
        const int wave = threadIdx.x >> 6;
        const int lane = threadIdx.x & 63;
        const int q    = lane >> 4;
        const int ml   = lane & 15;
        const int m0   = blockIdx.x * 64 + wave * 16;

        f32x4 acc[8];
        #pragma unroll
        for (int t = 0; t < 8; ++t) acc[t] = (f32x4){0.f, 0.f, 0.f, 0.f};

        long arow = m0 + ml; if (arow > N_NODES - 1) arow = N_NODES - 1;
        const float* xrow = x + arow * D_IN + q * 8;

        #pragma unroll
        for (int ks = 0; ks < 8; ++ks) {
            float4 xa = *(const float4*)(xrow + ks * 32);
            float4 xb = *(const float4*)(xrow + ks * 32 + 4);
            union { short8 s; unsigned int u[4]; } af;
            af.u[0] = pk2(xa.x, xa.y);
            af.u[1] = pk2(xa.z, xa.w);
            af.u[2] = pk2(xb.x, xb.y);
            af.u[3] = pk2(xb.z, xb.w);
            #pragma unroll
            for (int nt = 0; nt < 8; ++nt) {
                union { uint4 v; short8 s; } bu;
                bu.v = Bp[(long)(ks * 8 + nt) * 64 + lane];
                acc[nt] = __builtin_amdgcn_mfma_f32_16x16x32_bf16(af.s, bu.s, acc[nt], 0, 0, 0);
            }
        }

        unsigned short* o = (unsigned short*)smem + wave * 2048;
        #pragma unroll
        for (int nt = 0; nt < 8; ++nt) {
            float bn = bf[nt * 16 + ml];
            #pragma unroll
            for (int r = 0; r < 4; ++r) {
                float val = acc[nt][r] + bn;           // NO dinv here (decoupled)
                o[(q * 4 + r) * 128 + nt * 16 + ml] = f2bf(val);
            }
        }
        __syncthreads();
        #pragma unroll
        for (int i = 0; i < 4; ++i) {
            int fb = i * 1024 + lane * 16;
            int v = m0 + (fb >> 8);
            if (v < N_NODES) {
                uint4 val = *(const uint4*)((const char*)o + fb);
                *(uint4*)((char*)hsb + (long)v * 256 + (fb & 255)) = val;
            }
        }
    } else {
        // ---------------- scatter role ----------------
        int* hist  = (int*)smem;                 // 1024
        int* lofs  = hist + GPAD;                // 1024
        int* fill2 = lofs + GPAD;                // 1024
        int* base  = fill2 + GPAD;               // 1024
        int* part  = base + GPAD;                // 256
        unsigned int* stag = (unsigned int*)(part + 256);   // 2500
        int t = threadIdx.x;
        for (int i = t; i < GPAD; i += 256) { hist[i] = 0; fill2[i] = 0; }
        __syncthreads();
        int e0 = (blockIdx.x - GEMM_BLOCKS) * CHUNK;
        for (int i = t; i < CHUNK; i += 256)
            atomicAdd(&hist[col[e0 + i] >> 6], 1);
        __syncthreads();
        int h[4], p4 = 0;
        #pragma unroll
        for (int i = 0; i < 4; ++i) { h[i] = hist[4 * t + i]; p4 += h[i]; }
        part[t] = p4;
        __syncthreads();
        for (int d = 1; d < 256; d <<= 1) {
            int add = (t >= d) ? part[t - d] : 0;
            __syncthreads();
            part[t] += add;
            __syncthreads();
        }
        int ex = part[t] - p4;
        #pragma unroll
        for (int i = 0; i < 4; ++i) { lofs[4 * t + i] = ex; ex += h[i]; }
        __syncthreads();
        for (int g = t; g < G_BUCKETS; g += 256) {
            int c = hist[g];
            base[g] = c ? atomicAdd(&bfill[g], c) : 0;
        }
        for (int i = t; i < CHUNK; i += 256) {
            int c = col[e0 + i];
            int g = c >> 6;
            unsigned int u = (unsigned int)row[e0 + i] | ((unsigned int)(c & 63) << 16)
                           | ((unsigned int)g << 22);
            int lp = atomicAdd(&fill2[g], 1);
            stag[lofs[g] + lp] = u;
        }
        __syncthreads();
        for (int i = t; i < CHUNK; i += 256) {
            unsigned int u = stag[i];
            int g = u >> 22;
            eb[base[g] + (i - lofs[g])] = u;
        }
    }
}

// ---- per-bucket CSR build (segmented): node-sorted ushort rows; offs/ends/dinv ----
__global__ __launch_bounds__(256) void csr_build_k(const int* __restrict__ bfill,
                                                   const unsigned int* __restrict__ eb,
                                                   unsigned short* __restrict__ csr,
                                                   int* __restrict__ offs,
                                                   int* __restrict__ ends,
                                                   float* __restrict__ dinv) {
    __shared__ unsigned int stag[CAP];
    __shared__ unsigned short stag2[CAP];
    __shared__ int hist[64], lofs[64], fill[64];
    int t = threadIdx.x;
    int g = blockIdx.x;
    int s = g * CAP;
    int cnt = bfill[g] - s;
    if (t < 64) { hist[t] = 0; fill[t] = 0; }
    __syncthreads();
    for (int i = t; i < cnt; i += 256) {
        unsigned int u = eb[s + i];
        stag[i] = u;
        atomicAdd(&hist[(u >> 16) & 63], 1);
    }
    __syncthreads();
    if (t == 0) {
        int run = 0;
        for (int k = 0; k < 64; ++k) { lofs[k] = run; run += hist[k]; }
    }
    __syncthreads();
    if (t < 64) {
        int v = g * 64 + t;
        if (v < N_NODES) {
            offs[v] = s + lofs[t];
            ends[v] = s + lofs[t] + hist[t];
            dinv[v] = rsqrtf((float)hist[t] + 1.0f);   // +1 self loop
        }
    }
    for (int i = t; i < cnt; i += 256) {
        unsigned int u = stag[i];
        int nl = (u >> 16) & 63;
        int lp = atomicAdd(&fill[nl], 1);
        stag2[lofs[nl] + lp] = (unsigned short)(u & 0xFFFF);
    }
    __syncthreads();
    for (int i = t; i < cnt; i += 256)
        csr[s + i] = stag2[i];
}

// ---- per-node aggregation, 4-deep MLP: 16 lanes/edge x uint4, 16 edges in flight/wave ----
__global__ __launch_bounds__(256) void aggregate_csr_k(const int* __restrict__ offs,
                                                       const int* __restrict__ ends,
                                                       const unsigned short* __restrict__ csr,
                                                       const uint4* __restrict__ hs4,
                                                       const float* __restrict__ dinv,
                                                       const float* __restrict__ bc,
                                                       uint4* __restrict__ feat4) {
    int v    = blockIdx.x * 4 + (threadIdx.x >> 6);
    int lane = threadIdx.x & 63;
    int grp  = lane >> 4, li = lane & 15;
    int s0 = offs[v], s1 = ends[v];

    float a[8] = {0.f, 0.f, 0.f, 0.f, 0.f, 0.f, 0.f, 0.f};
    int i = s0 + grp;
    for (; i + 12 < s1; i += 16) {            // 4 gathers in flight per group
        int r0 = csr[i], r1 = csr[i + 4], r2 = csr[i + 8], r3 = csr[i + 12];
        uint4 u0 = hs4[r0 * 16 + li];
        uint4 u1 = hs4[r1 * 16 + li];
        uint4 u2 = hs4[r2 * 16 + li];
        uint4 u3 = hs4[r3 * 16 + li];
        float d0 = dinv[r0], d1 = dinv[r1], d2 = dinv[r2], d3 = dinv[r3];
        a[0] = fmaf(d0, bflo(u0.x), a[0]); a[1] = fmaf(d0, bfhi(u0.x), a[1]);
        a[2] = fmaf(d0, bflo(u0.y), a[2]); a[3] = fmaf(d0, bfhi(u0.y), a[3]);
        a[4] = fmaf(d0, bflo(u0.z), a[4]); a[5] = fmaf(d0, bfhi(u0.z), a[5]);
        a[6] = fmaf(d0, bflo(u0.w), a[6]); a[7] = fmaf(d0, bfhi(u0.w), a[7]);
        a[0] = fmaf(d1, bflo(u1.x), a[0]); a[1] = fmaf(d1, bfhi(u1.x), a[1]);
        a[2] = fmaf(d1, bflo(u1.y), a[2]); a[3] = fmaf(d1, bfhi(u1.y), a[3]);
        a[4] = fmaf(d1, bflo(u1.z), a[4]); a[5] = fmaf(d1, bfhi(u1.z), a[5]);
        a[6] = fmaf(d1, bflo(u1.w), a[6]); a[7] = fmaf(d1, bfhi(u1.w), a[7]);
        a[0] = fmaf(d2, bflo(u2.x), a[0]); a[1] = fmaf(d2, bfhi(u2.x), a[1]);
        a[2] = fmaf(d2, bflo(u2.y), a[2]); a[3] = fmaf(d2, bfhi(u2.y), a[3]);
        a[4] = fmaf(d2, bflo(u2.z), a[4]); a[5] = fmaf(d2, bfhi(u2.z), a[5]);
        a[6] = fmaf(d2, bflo(u2.w), a[6]); a[7] = fmaf(d2, bfhi(u2.w), a[7]);
        a[0] = fmaf(d3, bflo(u3.x), a[0]); a[1] = fmaf(d3, bfhi(u3.x), a[1]);
        a[2] = fmaf(d3, bflo(u3.y), a[2]); a[3] = fmaf(d3, bfhi(u3.y), a[3]);
        a[4] = fmaf(d3, bflo(u3.z), a[4]); a[5] = fmaf(d3, bfhi(u3.z), a[5]);
        a[6] = fmaf(d3, bflo(u3.w), a[6]); a[7] = fmaf(d3, bfhi(u3.w), a[7]);
    }
    for (; i < s1; i += 4) {                  // tail: up to 3 edges per group
        int r = csr[i];
        uint4 u = hs4[r * 16 + li];
        float d = dinv[r];
        a[0] = fmaf(d, bflo(u.x), a[0]); a[1] = fmaf(d, bfhi(u.x), a[1]);
        a[2] = fmaf(d, bflo(u.y), a[2]); a[3] = fmaf(d, bfhi(u.y), a[3]);
        a[4] = fmaf(d, bflo(u.z), a[4]); a[5] = fmaf(d, bfhi(u.z), a[5]);
        a[6] = fmaf(d, bflo(u.w), a[6]); a[7] = fmaf(d, bfhi(u.w), a[7]);
    }
    // reduce across the 4 groups (lane bits 4,5)
    #pragma unroll
    for (int j = 0; j < 8; ++j) {
        a[j] += __shfl_xor(a[j], 16);
        a[j] += __shfl_xor(a[j], 32);
    }
    if (grp == 0) {
        uint4 su = hs4[v * 16 + li];           // self-loop term (unscaled h)
        float dv = dinv[v];
        float4 b0 = *(const float4*)(bc + li * 8);
        float4 b1 = *(const float4*)(bc + li * 8 + 4);
        float f0 = dv * (a[0] + dv * bflo(su.x)) + b0.x;
        float f1 = dv * (a[1] + dv * bfhi(su.x)) + b0.y;
        float f2 = dv * (a[2] + dv * bflo(su.y)) + b0.z;
        float f3 = dv * (a[3] + dv * bfhi(su.y)) + b0.w;
        float f4 = dv * (a[4] + dv * bflo(su.z)) + b1.x;
        float f5 = dv * (a[5] + dv * bfhi(su.z)) + b1.y;
        float f6 = dv * (a[6] + dv * bflo(su.w)) + b1.z;
        float f7 = dv * (a[7] + dv * bfhi(su.w)) + b1.w;
        uint4 o;
        o.x = pk2(f0, f1); o.y = pk2(f2, f3); o.z = pk2(f4, f5); o.w = pk2(f6, f7);
        feat4[v * 16 + li] = o;
    }
}

// ---------------- logits[e] = dot(feat[src], feat[dst]) — 16 lanes/edge ----------------
__global__ void score_k(const int* __restrict__ src, const int* __restrict__ dst,
                        const uint4* __restrict__ feat4, float* __restrict__ out) {
    int gid = blockIdx.x * blockDim.x + threadIdx.x;
    int e = gid >> 4;
    int c = gid & 15;
    if (e >= N_PRED) return;
    int a = src[e], b = dst[e];
    uint4 ua = feat4[(long)a * 16 + c];
    uint4 ub = feat4[(long)b * 16 + c];
    float p = bflo(ua.x) * bflo(ub.x) + bfhi(ua.x) * bfhi(ub.x)
            + bflo(ua.y) * bflo(ub.y) + bfhi(ua.y) * bfhi(ub.y)
            + bflo(ua.z) * bflo(ub.z) + bfhi(ua.z) * bfhi(ub.z)
            + bflo(ua.w) * bflo(ub.w) + bfhi(ua.w) * bfhi(ub.w);
    #pragma unroll
    for (int m = 8; m; m >>= 1) p += __shfl_xor(p, m, 16);
    if (c == 0) out[e] = p;
}

extern "C" void kernel_launch(void* const* d_in, const int* in_sizes, int n_in,
                              void* d_out, int out_size, void* d_ws, size_t ws_size,
                              hipStream_t stream) {
    const float* x   = (const float*)d_in[0];
    const int*   ei  = (const int*)  d_in[1];   // [2, N_PRED]
    const int*   pe  = (const int*)  d_in[2];   // [2, N_POS]
    const float* W1  = (const float*)d_in[3];
    const float* b1  = (const float*)d_in[4];
    const float* Wc  = (const float*)d_in[5];
    const float* bc  = (const float*)d_in[6];
    float* out = (float*)d_out;

    const int* pe_row = pe;            // source
    const int* pe_col = pe + N_POS;    // target (aggregation)
    const int* ei_src = ei;
    const int* ei_dst = ei + N_PRED;

    // workspace layout (16B-aligned blocks)
    char* w = (char*)d_ws;
    unsigned short* Bp = (unsigned short*)w;  w += 32768 * 2;      // 64 KB
    float* bf    = (float*)w;                 w += 128 * 4;
    float* dinv  = (float*)w;                 w += 50000 * 4;
    int*   bfill = (int*)w;                   w += GPAD * 4;
    int*   offs  = (int*)w;                   w += 50000 * 4;
    int*   ends  = (int*)w;                   w += 50000 * 4;
    unsigned int* eb = (unsigned int*)w;      w += (long)G_BUCKETS * CAP * 4;    // 12.81 MB
    unsigned short* csr = (unsigned short*)w; w += (long)G_BUCKETS * CAP * 2;    // 6.4 MB
    unsigned short* hsb   = (unsigned short*)w;  w += (long)N_NODES * D_OUT * 2; // 12.8 MB
    unsigned short* featb = (unsigned short*)w;  // 12.8 MB

    // L1: weight fuse + cursor init (129 blocks: 0..127 weights, 128 cursors)
    fuse_weights_k<<<129, 256, 0, stream>>>(W1, Wc, b1, Bp, bf, bfill);

    // L2: fused gemm (782 blocks) || scatter (640 blocks) — independent roles
    scatter_gemm_k<<<GEMM_BLOCKS + SB, 256, 0, stream>>>(pe_row, pe_col, bfill, eb,
                                                         x, (const uint4*)Bp, bf, hsb);

    // L3: segmented CSR build (also emits offs/ends/dinv)
    csr_build_k   <<<G_BUCKETS, 256, 0, stream>>>(bfill, eb, csr, offs, ends, dinv);

    // L4: aggregation + finalize (dinv applied on the fly, 4-deep gather MLP)
    aggregate_csr_k<<<N_NODES / 4, 256, 0, stream>>>(offs, ends, csr, (const uint4*)hsb,
                                                     dinv, bc, (uint4*)featb);

    // L5: scoring
    score_k       <<<(int)(((long)N_PRED * 16) / 256), 256, 0, stream>>>(
                      ei_src, ei_dst, (const uint4*)featb, out);
}